// Round 5
// baseline (139.449 us; speedup 1.0000x reference)
//
#include <hip/hip_runtime.h>
#include <stdint.h>
#include <math.h>

// Validated semantics (r17/r18 green): printed reference, fp32 in/out.
//   p[b,j] = mean_h sigmoid(delta/sqrt(32)),
//   delta[j,b,h] = sum_e D_e*(U+V),  D_e = (s_e-mu_s)-(o_e-mu_o)
//   Folded mu: sum_e D*w = sum_e (s-o)*w - ((sum s - sum o)/256)*sum_e w
//   U[h,e,j] = sum_{d in h} QwT[d,j]*Wk[d,e],  QwT = Qp[256+j]@Wq^T
//   V[b,h,e] = sum_{d in h} (Pq[b,d]+bq[d])*Wk[d,e],  Pq = pe[b]@Wq^T
//   new_state[b,e,l<256]=state; l>=256: p*s_l+(1-p)*o_{l-256}
//   atten[b,l,s]: l<256 -> 1 at s=l; else p at s=l, 1-p at s=l+256.
// This round: algebraic restructure of the prologue. T[h,e,c] =
// sum_{d in h} Wk[d,e]*Wq[d,c] lets U = T x QpT and V = pe x Tt + Tb,
// deleting QwT/Pq/WqT stages. 5 kernels -> 4 (k_A, k_B, k_delta, k_out);
// k_delta/k_out byte-identical to the 131us build. ws is 256 MiB
// (fill WRITE_SIZE=262144 KB), so the extra 4 MB of T/Tt is free.

// d_ws layout (floats)
#define WS_P    0        // [32 b][256 j]  sum_h sigmoid
#define WS_U    81920    // [8 h][256 e][256 j]
#define WS_V    606208   // [32 b][8 h][256 e]
#define WS_QPT  671744   // [256 c][256 j]  QpT[c][j] = Qp[256+j][c]
#define WS_T    737280   // [8 h][256 e][256 c]
#define WS_TT   1261568  // [8 h][256 c][256 e]
#define WS_TB   1785856  // [8 h][256 e]
// end 1787904 floats = 6.8 MB << 256 MiB ws

// ---------------------------------------------------------------------------
// K_A: dep-free prologue. 192 blocks x 256.
//   [0,64):   QpT transpose via padded 32x32 LDS tiles.
//   [64,192): (h, e-tile16): T[h][e][c], Tt[h][c][e], Tb[h][e].
__global__ void __launch_bounds__(256)
k_A(const float* __restrict__ Qp, const float* __restrict__ Wq,
    const float* __restrict__ Wk, const float* __restrict__ bq,
    float* __restrict__ ws) {
  int bid = blockIdx.x, t = threadIdx.x;
  if (bid < 64) {                       // QpT[c][j] = Qp[256+j][c]
    __shared__ float tile[32][33];
    int tr = bid >> 3, tc = bid & 7;    // row-tile (j), col-tile (c)
    int c = t & 31, r0 = t >> 5;
    #pragma unroll
    for (int k = 0; k < 4; ++k) {       // load coalesced
      int r = r0 + (k << 3);
      tile[r][c] = Qp[65536 + (size_t)(tr * 32 + r) * 256 + tc * 32 + c];
    }
    __syncthreads();
    #pragma unroll
    for (int k = 0; k < 4; ++k) {       // store transposed, coalesced
      int r = r0 + (k << 3);
      ws[WS_QPT + (size_t)(tc * 32 + r) * 256 + tr * 32 + c] = tile[c][r];
    }
  } else {                              // T / Tt / Tb
    int idx = bid - 64;
    int h = idx >> 4, e0 = (idx & 15) << 4;   // e-tile of 16
    __shared__ float wk_s[32][17];      // Wk[d in h][e0..e0+15]
    __shared__ float bq_s[32];
    {                                   // stage Wk tile (64B segments) + bq
      int d = t >> 4, i = t & 15;
      wk_s[d][i]      = Wk[(size_t)(h * 32 + d) * 256 + e0 + i];
      wk_s[d + 16][i] = Wk[(size_t)(h * 32 + d + 16) * 256 + e0 + i];
      if (t < 32) bq_s[t] = bq[h * 32 + t];
    }
    __syncthreads();
    float acc[16];
    #pragma unroll
    for (int i = 0; i < 16; ++i) acc[i] = 0.f;
    const float* __restrict__ wqp = Wq + (size_t)h * 8192 + t;  // Wq[h*32][c=t]
    #pragma unroll 4
    for (int d = 0; d < 32; ++d) {
      float wq = wqp[d << 8];           // coalesced; wk_s broadcast
      #pragma unroll
      for (int i = 0; i < 16; ++i) acc[i] += wk_s[d][i] * wq;
    }
    float* Th  = ws + WS_T  + (h << 16);
    float* Tth = ws + WS_TT + (h << 16);
    #pragma unroll
    for (int i = 0; i < 16; ++i)        // T[h][e0+i][c=t], coalesced
      Th[(size_t)(e0 + i) * 256 + t] = acc[i];
    #pragma unroll
    for (int k = 0; k < 4; ++k) {       // Tt[h][c=t][e0..]: 4x float4 per lane
      float4 v; v.x = acc[4*k]; v.y = acc[4*k+1]; v.z = acc[4*k+2]; v.w = acc[4*k+3];
      *(float4*)(Tth + (size_t)t * 256 + e0 + 4 * k) = v;
    }
    if (t < 16) {                       // Tb[h][e0+t] = sum_d bq[d]*Wk[d][e]
      float tb = 0.f;
      #pragma unroll
      for (int d = 0; d < 32; ++d) tb += bq_s[d] * wk_s[d][t];
      ws[WS_TB + h * 256 + e0 + t] = tb;
    }
  }
}

// ---------------------------------------------------------------------------
// K_B: U and V. 512 blocks x 256.
//   [0,256):   (h, e-tile8): U[h][e][j] = sum_c T[h][e][c]*QpT[c][j].
//              T rows staged in LDS (broadcast), QpT streamed coalesced;
//              each load feeds 8 FMAs -> latency-immune.
//   [256,512): (b,h): V[b][h][e] = sum_c pe[b][c]*Tt[h][c][e] + Tb[h][e].
__global__ void __launch_bounds__(256)
k_B(float* __restrict__ ws) {
  int bid = blockIdx.x, t = threadIdx.x;
  if (bid < 256) {
    int h = bid >> 5, e0 = (bid & 31) << 3;
    __shared__ float Ts[8][256];
    const float* __restrict__ Th = ws + WS_T + (h << 16) + (size_t)e0 * 256;
    #pragma unroll
    for (int i = 0; i < 8; ++i) Ts[i][t] = Th[(size_t)i * 256 + t];
    __syncthreads();
    float acc[8];
    #pragma unroll
    for (int i = 0; i < 8; ++i) acc[i] = 0.f;
    const float* __restrict__ QT = ws + WS_QPT + t;
    #pragma unroll 4
    for (int c = 0; c < 256; ++c) {
      float q = QT[c << 8];             // coalesced; Ts broadcast
      #pragma unroll
      for (int i = 0; i < 8; ++i) acc[i] += Ts[i][c] * q;
    }
    float* Uh = ws + WS_U + (h << 16) + (size_t)e0 * 256;
    #pragma unroll
    for (int i = 0; i < 8; ++i) Uh[(size_t)i * 256 + t] = acc[i];
  } else {
    int idx = bid - 256, b = idx >> 3, h = idx & 7;
    __shared__ float pe_s[256];
    {                                   // pe[b][c] analytic
      int k2 = t & ~1;                  // arange value 2k
      float div = expf((float)k2 * (-9.210340371976184f / 256.f));
      float a = (float)b * div;
      pe_s[t] = (t & 1) ? cosf(a) : sinf(a);
    }
    __syncthreads();
    float acc = ws[WS_TB + h * 256 + t];
    const float* __restrict__ Tth = ws + WS_TT + (h << 16) + t;
    #pragma unroll 16
    for (int c = 0; c < 256; ++c)
      acc += pe_s[c] * Tth[c << 8];     // coalesced stream
    ws[WS_V + ((b << 3) + h) * 256 + t] = acc;
  }
}

// ---------------------------------------------------------------------------
// K3: delta. 256 blocks = (b, j-tile of 32) x 256 threads. (unchanged)
__global__ void __launch_bounds__(256)
k_delta(const float* __restrict__ state, const float* __restrict__ obs,
        float* __restrict__ ws) {
  int b = blockIdx.x >> 3, jt = (blockIdx.x & 7) << 5;
  int t = threadIdx.x;
  __shared__ float Xs[256][33];         // X[e][j], +1 pad -> <=2-way (free)
  __shared__ float Vs[2048];            // V[b][h][e] slice
  __shared__ float pd[8][8][32];        // [eg][h][j] partial sum X*w
  __shared__ float pw[8][8][32];        // [eg][h][j] partial sum w
  __shared__ float px[8][32];           // [eg][j]    partial sum X (reused)
  {                                     // stage: (es 0..31, jq 0..7) float4
    int es = t >> 3, jq = t & 7;
    const float* sp = state + (size_t)b * 131072 + 256 + jt + (jq << 2);
    const float* op = obs   + (size_t)b * 65536  + jt + (jq << 2);
    #pragma unroll
    for (int k = 0; k < 8; ++k) {
      int e = es + (k << 5);
      float4 s4 = *(const float4*)(sp + (size_t)e * 512);
      float4 o4 = *(const float4*)(op + (size_t)e * 256);
      float* xr = &Xs[e][jq << 2];
      xr[0] = s4.x - o4.x; xr[1] = s4.y - o4.y;
      xr[2] = s4.z - o4.z; xr[3] = s4.w - o4.w;
    }
    for (int i = t; i < 2048; i += 256) Vs[i] = ws[WS_V + (b << 11) + i];
  }
  __syncthreads();
  int j = t & 31, eg = t >> 5, e0 = eg << 5;
  {                                     // a_x partial (h-independent)
    float ax = 0.f;
    #pragma unroll
    for (int ei = 0; ei < 32; ++ei) ax += Xs[e0 + ei][j];
    px[eg][j] = ax;
  }
  const float* __restrict__ Ub = ws + WS_U + jt + j;
  #pragma unroll
  for (int h = 0; h < 8; ++h) {
    float dacc = 0.f, wacc = 0.f;
    const float* __restrict__ Uh = Ub + (h << 16) + (e0 << 8);
    const float* __restrict__ Vh = Vs + (h << 8) + e0;
    #pragma unroll 16
    for (int ei = 0; ei < 32; ++ei) {
      float w = Uh[ei << 8] + Vh[ei];
      dacc += Xs[e0 + ei][j] * w;
      wacc += w;
    }
    pd[eg][h][j] = dacc;
    pw[eg][h][j] = wacc;
  }
  __syncthreads();
  int h2 = t >> 5, j2 = t & 31;         // thread -> (h, j) for the merge
  float D = 0.f, W = 0.f, X = 0.f;
  #pragma unroll
  for (int g = 0; g < 8; ++g) {
    D += pd[g][h2][j2];
    W += pw[g][h2][j2];
    X += px[g][j2];
  }
  float delta = D - X * (1.f / 256.f) * W;
  float sig = 1.f / (1.f + __expf(-delta * 0.17677669529663687f)); // /sqrt(32)
  __syncthreads();
  px[h2][j2] = sig;                     // reuse px as [h][j] sigmoid buffer
  __syncthreads();
  if (t < 32) {
    float acc = 0.f;
    #pragma unroll
    for (int h = 0; h < 8; ++h) acc += px[h][t];
    ws[WS_P + (b << 8) + jt + t] = acc; // sum_h; k_out applies *0.125
  }
}

// ---------------------------------------------------------------------------
// K4 fused output. 16384 blocks: [0,4096) new_state (2 rows/block, float4);
// rest atten float4s (write-bound). (unchanged)
__global__ void __launch_bounds__(256)
k_out(const float* __restrict__ state, const float* __restrict__ obs,
      const float* __restrict__ ws, float* __restrict__ out) {
  int bid = blockIdx.x, t = threadIdx.x;
  if (bid < 4096) {                     // new_state rows, float4/thread
    int row = (bid << 1) | (t >> 7);    // row = b*256 + e
    int tt = t & 127;                   // cols l = 4tt..4tt+3
    int b = row >> 8;
    float4 sv = ((const float4*)(state + (size_t)row * 512))[tt];
    float4* wrow = (float4*)(out + (size_t)row * 512);
    if (tt < 64) {
      wrow[tt] = sv;                    // l < 256: identity
    } else {
      float4 ov = ((const float4*)(obs + (size_t)row * 256))[tt - 64];
      float4 p4 = ((const float4*)(ws + WS_P + b * 256))[tt - 64];
      p4.x *= 0.125f; p4.y *= 0.125f; p4.z *= 0.125f; p4.w *= 0.125f;
      float4 r;
      r.x = p4.x * sv.x + (1.f - p4.x) * ov.x;
      r.y = p4.y * sv.y + (1.f - p4.y) * ov.y;
      r.z = p4.z * sv.z + (1.f - p4.z) * ov.z;
      r.w = p4.w * sv.w + (1.f - p4.w) * ov.w;
      wrow[tt] = r;
    }
  } else {                              // atten, one float4 per thread
    int g4 = (bid - 4096) * 256 + t;    // 0..3145727
    int r = g4 / 192, c = g4 - r * 192; // r = b*512 + l
    int b = r >> 9, l = r & 511;
    int s0 = c << 2;
    float v[4] = {0.f, 0.f, 0.f, 0.f};
    if (l < 256) {
      if (l >= s0 && l < s0 + 4) v[l - s0] = 1.0f;
    } else {
      float p = ws[WS_P + b * 256 + (l - 256)] * 0.125f;
      if (l >= s0 && l < s0 + 4) v[l - s0] = p;
      int s2 = l + 256;
      if (s2 >= s0 && s2 < s0 + 4) v[s2 - s0] = 1.0f - p;
    }
    float4 val; val.x = v[0]; val.y = v[1]; val.z = v[2]; val.w = v[3];
    ((float4*)(out + 4194304))[g4] = val;
  }
}

extern "C" void kernel_launch(void* const* d_in, const int* in_sizes, int n_in,
                              void* d_out, int out_size, void* d_ws, size_t ws_size,
                              hipStream_t stream) {
  const float *state = nullptr, *obs = nullptr, *Qp = nullptr;
  const float *Wq = nullptr, *Wk = nullptr, *bq = nullptr, *bk = nullptr;
  for (int i = 0; i < n_in; ++i) {
    int s = in_sizes[i];
    const float* p = (const float*)d_in[i];
    if      (s == 4194304) state = p;
    else if (s == 2097152) obs = p;
    else if (s == 131072)  Qp = p;
    else if (s == 65536)   { if (!Wq) Wq = p; else Wk = p; }
    else if (s == 256)     { if (!bq) bq = p; else bk = p; }
  }
  (void)bk;                             // cancels in the 2-way softmax
  float* out = (float*)d_out;
  float* ws  = (float*)d_ws;

  k_A    <<<192,   256, 0, stream>>>(Qp, Wq, Wk, bq, ws);
  k_B    <<<512,   256, 0, stream>>>(ws);
  k_delta<<<256,   256, 0, stream>>>(state, obs, ws);
  k_out  <<<16384, 256, 0, stream>>>(state, obs, ws, out);
}

// Round 6
// 126.557 us; speedup vs baseline: 1.1019x; 1.1019x over previous
//
#include <hip/hip_runtime.h>
#include <stdint.h>
#include <math.h>

// Validated semantics (r17/r18 green): printed reference, fp32 in/out.
//   p[b,j] = mean_h sigmoid(delta/sqrt(32)),
//   delta[j,b,h] = sum_e D_e*(U+V),  D_e = (s_e-mu_s)-(o_e-mu_o)
//   Folded mu: sum_e D*w = sum_e (s-o)*w - ((sum s - sum o)/256)*sum_e w
//   U[h,e,j] = sum_{d in h} QwT[d,j]*Wk[d,e],  QwT = Qp[256+j]@Wq^T
//   V[b,h,e] = sum_{d in h} (Pq[b,d]+bq[d])*Wk[d,e],  Pq = pe[b]@Wq^T
//   new_state[b,e,l<256]=state; l>=256: p*s_l+(1-p)*o_{l-256}
//   atten[b,l,s]: l<256 -> 1 at s=l; else p at s=l, 1-p at s=l+256.
// r5 post-mortem: T-form inflated U's MACs 4x (134M vs 33.6M) -> regression.
// This round: revert to the r4 131.2us build; two local fixes only:
//   (a) k_uv U-half = (h, e-tile8) blocks, Wk tile in LDS, 8 FMAs/load
//       (QwT L2 traffic 64->8 MB, same math);
//   (b) k_out nontemporal stores (67 MB write-once stream stops evicting
//       state/obs/P from L2).

// d_ws layout (floats) — r4 layout
#define WS_P    0        // [32 b][256 j]  sum_h sigmoid
#define WS_QWT  8192     // [256 d][256 j]
#define WS_PQ   73728    // [32 b][256 d]
#define WS_U    81920    // [8 h][256 e][256 j]
#define WS_V    606208   // [32 b][8 h][256 e]
#define WS_QPT  671744   // [256 e][256 j]  QpT[e][j] = Qp[256+j][e]
#define WS_WQT  737280   // [256 e][256 d]  WqT[e][d] = Wq[d][e]
// end 802816 floats = 3.06 MB (ws is 256 MiB per fill WRITE_SIZE)

typedef float vf4 __attribute__((ext_vector_type(4)));
__device__ __forceinline__ void nt_store4(float* p, float x, float y,
                                          float z, float w) {
  vf4 v; v.x = x; v.y = y; v.z = z; v.w = w;
  __builtin_nontemporal_store(v, (vf4*)p);
}

// ---------------------------------------------------------------------------
// K0 transpose: QpT and WqT via padded 32x32 LDS tiles. 128 blocks x 256.
__global__ void __launch_bounds__(256)
k_tr(const float* __restrict__ Qp, const float* __restrict__ Wq,
     float* __restrict__ ws) {
  __shared__ float tile[32][33];
  int bid = blockIdx.x, t = threadIdx.x;
  const float* src; float* dst; int ti;
  if (bid < 64) { src = Qp + 65536; dst = ws + WS_QPT; ti = bid; }
  else          { src = Wq;         dst = ws + WS_WQT; ti = bid - 64; }
  int tr = ti >> 3, tc = ti & 7;        // row-tile (j/d), col-tile (e)
  int c = t & 31, r0 = t >> 5;
  #pragma unroll
  for (int k = 0; k < 4; ++k) {         // load src tile, coalesced
    int r = r0 + (k << 3);
    tile[r][c] = src[(size_t)(tr * 32 + r) * 256 + tc * 32 + c];
  }
  __syncthreads();
  #pragma unroll
  for (int k = 0; k < 4; ++k) {         // store transposed, coalesced
    int r = r0 + (k << 3);
    dst[(size_t)(tc * 32 + r) * 256 + tr * 32 + c] = tile[c][r];
  }
}

// ---------------------------------------------------------------------------
// K1 prologue: QwT (256 blocks), Pq (32). 288 blocks x 256.
// out[t] = sum_e lvec[e] * GT[e][t] — lvec broadcast from LDS, GT a dense
// lane-coalesced L2 stream. No syncs inside the loop.
__global__ void __launch_bounds__(256)
k_pro(const float* __restrict__ Wq, float* __restrict__ ws) {
  int bid = blockIdx.x, t = threadIdx.x;
  __shared__ float lvec[256];
  const float* __restrict__ GT; float* dst;
  if (bid < 256) {                      // QwT[d][j] = sum_e Wq[d][e]*QpT[e][j]
    int d = bid;
    lvec[t] = Wq[(size_t)d * 256 + t];
    GT = ws + WS_QPT; dst = ws + WS_QWT + d * 256;
  } else {                              // Pq[b][d] = sum_e pe[b][e]*WqT[e][d]
    int b = bid - 256;
    int k2 = t & ~1;                    // arange value 2k
    float div = expf((float)k2 * (-9.210340371976184f / 256.f));
    float a = (float)b * div;
    lvec[t] = (t & 1) ? cosf(a) : sinf(a);
    GT = ws + WS_WQT; dst = ws + WS_PQ + b * 256;
  }
  __syncthreads();
  float acc = 0.f;
  #pragma unroll 8
  for (int e = 0; e < 256; ++e)
    acc += lvec[e] * GT[(e << 8) + t];
  dst[t] = acc;
}

// ---------------------------------------------------------------------------
// K2: U[h][e][j] and V[b][h][e].  512 blocks x 256.
//   [0,256):   U, (h, e-tile8): Wk tile staged in LDS (broadcast reads),
//              QwT streamed coalesced, 8 FMAs per load.
//   [256,512): V, (b,h): unchanged math.
__global__ void __launch_bounds__(256)
k_uv(const float* __restrict__ Wk, const float* __restrict__ bq,
     float* __restrict__ ws) {
  int bid = blockIdx.x, t = threadIdx.x;
  if (bid < 256) {
    int h = bid >> 5, e0 = (bid & 31) << 3;
    __shared__ float wk_s[32][9];       // [d in h][e0..e0+7], +1 pad
    {
      int d = t >> 3, i = t & 7;        // 256 threads cover 32x8
      wk_s[d][i] = Wk[(size_t)(h * 32 + d) * 256 + e0 + i];
    }
    __syncthreads();
    float acc[8] = {0.f, 0.f, 0.f, 0.f, 0.f, 0.f, 0.f, 0.f};
    const float* __restrict__ Qw = ws + WS_QWT + t;
    #pragma unroll 4
    for (int d = 0; d < 32; ++d) {
      float q = Qw[((h << 5) + d) << 8];  // coalesced; wk_s broadcast
      #pragma unroll
      for (int i = 0; i < 8; ++i) acc[i] += wk_s[d][i] * q;
    }
    float* Uh = ws + WS_U + (h << 16) + (size_t)e0 * 256;
    #pragma unroll
    for (int i = 0; i < 8; ++i) Uh[(size_t)i * 256 + t] = acc[i];
  } else {
    int idx = bid - 256, b = idx >> 3, h = idx & 7;
    float acc = 0.f;
#pragma unroll 8
    for (int dd = 0; dd < 32; ++dd) {
      int d = h * 32 + dd;
      acc += (ws[WS_PQ + b * 256 + d] + bq[d]) * Wk[(size_t)d * 256 + t];
    }
    ws[WS_V + ((b << 3) + h) * 256 + t] = acc;
  }
}

// ---------------------------------------------------------------------------
// K3: delta. 256 blocks = (b, j-tile of 32) x 256 threads. (r4, unchanged)
__global__ void __launch_bounds__(256)
k_delta(const float* __restrict__ state, const float* __restrict__ obs,
        float* __restrict__ ws) {
  int b = blockIdx.x >> 3, jt = (blockIdx.x & 7) << 5;
  int t = threadIdx.x;
  __shared__ float Xs[256][33];         // X[e][j], +1 pad -> <=2-way (free)
  __shared__ float Vs[2048];            // V[b][h][e] slice
  __shared__ float pd[8][8][32];        // [eg][h][j] partial sum X*w
  __shared__ float pw[8][8][32];        // [eg][h][j] partial sum w
  __shared__ float px[8][32];           // [eg][j]    partial sum X (reused)
  {                                     // stage: (es 0..31, jq 0..7) float4
    int es = t >> 3, jq = t & 7;
    const float* sp = state + (size_t)b * 131072 + 256 + jt + (jq << 2);
    const float* op = obs   + (size_t)b * 65536  + jt + (jq << 2);
    #pragma unroll
    for (int k = 0; k < 8; ++k) {
      int e = es + (k << 5);
      float4 s4 = *(const float4*)(sp + (size_t)e * 512);
      float4 o4 = *(const float4*)(op + (size_t)e * 256);
      float* xr = &Xs[e][jq << 2];
      xr[0] = s4.x - o4.x; xr[1] = s4.y - o4.y;
      xr[2] = s4.z - o4.z; xr[3] = s4.w - o4.w;
    }
    for (int i = t; i < 2048; i += 256) Vs[i] = ws[WS_V + (b << 11) + i];
  }
  __syncthreads();
  int j = t & 31, eg = t >> 5, e0 = eg << 5;
  {                                     // a_x partial (h-independent)
    float ax = 0.f;
    #pragma unroll
    for (int ei = 0; ei < 32; ++ei) ax += Xs[e0 + ei][j];
    px[eg][j] = ax;
  }
  const float* __restrict__ Ub = ws + WS_U + jt + j;
  #pragma unroll
  for (int h = 0; h < 8; ++h) {
    float dacc = 0.f, wacc = 0.f;
    const float* __restrict__ Uh = Ub + (h << 16) + (e0 << 8);
    const float* __restrict__ Vh = Vs + (h << 8) + e0;
    #pragma unroll 16
    for (int ei = 0; ei < 32; ++ei) {
      float w = Uh[ei << 8] + Vh[ei];
      dacc += Xs[e0 + ei][j] * w;
      wacc += w;
    }
    pd[eg][h][j] = dacc;
    pw[eg][h][j] = wacc;
  }
  __syncthreads();
  int h2 = t >> 5, j2 = t & 31;         // thread -> (h, j) for the merge
  float D = 0.f, W = 0.f, X = 0.f;
  #pragma unroll
  for (int g = 0; g < 8; ++g) {
    D += pd[g][h2][j2];
    W += pw[g][h2][j2];
    X += px[g][j2];
  }
  float delta = D - X * (1.f / 256.f) * W;
  float sig = 1.f / (1.f + __expf(-delta * 0.17677669529663687f)); // /sqrt(32)
  __syncthreads();
  px[h2][j2] = sig;                     // reuse px as [h][j] sigmoid buffer
  __syncthreads();
  if (t < 32) {
    float acc = 0.f;
    #pragma unroll
    for (int h = 0; h < 8; ++h) acc += px[h][t];
    ws[WS_P + (b << 8) + jt + t] = acc; // sum_h; k_out applies *0.125
  }
}

// ---------------------------------------------------------------------------
// K4 fused output. 16384 blocks: [0,4096) new_state (2 rows/block, float4);
// rest atten float4s. All output stores nontemporal (write-once stream).
__global__ void __launch_bounds__(256)
k_out(const float* __restrict__ state, const float* __restrict__ obs,
      const float* __restrict__ ws, float* __restrict__ out) {
  int bid = blockIdx.x, t = threadIdx.x;
  if (bid < 4096) {                     // new_state rows, float4/thread
    int row = (bid << 1) | (t >> 7);    // row = b*256 + e
    int tt = t & 127;                   // cols l = 4tt..4tt+3
    int b = row >> 8;
    float4 sv = ((const float4*)(state + (size_t)row * 512))[tt];
    float* wrow = out + (size_t)row * 512 + (tt << 2);
    if (tt < 64) {
      nt_store4(wrow, sv.x, sv.y, sv.z, sv.w);  // l < 256: identity
    } else {
      float4 ov = ((const float4*)(obs + (size_t)row * 256))[tt - 64];
      float4 p4 = ((const float4*)(ws + WS_P + b * 256))[tt - 64];
      p4.x *= 0.125f; p4.y *= 0.125f; p4.z *= 0.125f; p4.w *= 0.125f;
      nt_store4(wrow,
                p4.x * sv.x + (1.f - p4.x) * ov.x,
                p4.y * sv.y + (1.f - p4.y) * ov.y,
                p4.z * sv.z + (1.f - p4.z) * ov.z,
                p4.w * sv.w + (1.f - p4.w) * ov.w);
    }
  } else {                              // atten, one float4 per thread
    int g4 = (bid - 4096) * 256 + t;    // 0..3145727
    int r = g4 / 192, c = g4 - r * 192; // r = b*512 + l
    int b = r >> 9, l = r & 511;
    int s0 = c << 2;
    float v[4] = {0.f, 0.f, 0.f, 0.f};
    if (l < 256) {
      if (l >= s0 && l < s0 + 4) v[l - s0] = 1.0f;
    } else {
      float p = ws[WS_P + b * 256 + (l - 256)] * 0.125f;
      if (l >= s0 && l < s0 + 4) v[l - s0] = p;
      int s2 = l + 256;
      if (s2 >= s0 && s2 < s0 + 4) v[s2 - s0] = 1.0f - p;
    }
    nt_store4(out + 4194304 + ((size_t)g4 << 2), v[0], v[1], v[2], v[3]);
  }
}

extern "C" void kernel_launch(void* const* d_in, const int* in_sizes, int n_in,
                              void* d_out, int out_size, void* d_ws, size_t ws_size,
                              hipStream_t stream) {
  const float *state = nullptr, *obs = nullptr, *Qp = nullptr;
  const float *Wq = nullptr, *Wk = nullptr, *bq = nullptr, *bk = nullptr;
  for (int i = 0; i < n_in; ++i) {
    int s = in_sizes[i];
    const float* p = (const float*)d_in[i];
    if      (s == 4194304) state = p;
    else if (s == 2097152) obs = p;
    else if (s == 131072)  Qp = p;
    else if (s == 65536)   { if (!Wq) Wq = p; else Wk = p; }
    else if (s == 256)     { if (!bq) bq = p; else bk = p; }
  }
  (void)bk;                             // cancels in the 2-way softmax
  float* out = (float*)d_out;
  float* ws  = (float*)d_ws;

  k_tr   <<<128,   256, 0, stream>>>(Qp, Wq, ws);
  k_pro  <<<288,   256, 0, stream>>>(Wq, ws);
  k_uv   <<<512,   256, 0, stream>>>(Wk, bq, ws);
  k_delta<<<256,   256, 0, stream>>>(state, obs, ws);
  k_out  <<<16384, 256, 0, stream>>>(state, obs, ws, out);
}